// Round 7
// baseline (271.513 us; speedup 1.0000x reference)
//
#include <hip/hip_runtime.h>
#include <math.h>

#define NN 4096
#define LOG2E 1.4426950408889634f

typedef short short8 __attribute__((ext_vector_type(8)));
typedef float f32x4 __attribute__((ext_vector_type(4)));

// workspace layout (float offsets)
#define OFF_COMB   0u          // 4096*96
#define OFF_F1     393216u     // [head][i] 2*4096
#define OFF_F2     401408u     // [head][j] 2*4096
#define OFF_W2     409616u     // 32*96
#define OFF_B2     412688u     // 96 (+pad to 412800)
#define OFF_HT     412800u     // bf16 hT[64][4096] = 131072 float slots
#define OFF_PACK   543872u     // u64 bitmask [4096][64] = 524288 float slots
#define OFF_PART   1068160u    // part[i][NS][64], then lpart[i][NS][2]

__device__ inline unsigned short f2bf(float x) {
  unsigned u = __float_as_uint(x);
  unsigned r = u + 0x7FFFu + ((u >> 16) & 1u);   // RNE
  return (unsigned short)(r >> 16);
}

// ---- Kernel 0: pack adjacency to bitmask (64 MB -> 2 MB), ballot ------------
__global__ __launch_bounds__(256) void k_pack(
    const int* __restrict__ adj, unsigned long long* __restrict__ pack)
{
  size_t t = (size_t)blockIdx.x * 256 + threadIdx.x;
  unsigned long long m = __ballot(adj[t] != 0);
  if ((threadIdx.x & 63) == 0) pack[t >> 6] = m;
}

// ---- Kernel 1: comb = relu(LN(embed)); tail blocks fold W2/B2 (mha path) ----
__global__ __launch_bounds__(256) void k_comb(
    const float* __restrict__ spatial, const float* __restrict__ genomic,
    const float* __restrict__ temporal,
    const float* __restrict__ sp_w, const float* __restrict__ sp_b,
    const float* __restrict__ sp_lg, const float* __restrict__ sp_lb,
    const float* __restrict__ ge_w, const float* __restrict__ ge_b,
    const float* __restrict__ ge_lg, const float* __restrict__ ge_lb,
    const float* __restrict__ te_w, const float* __restrict__ te_b,
    const float* __restrict__ te_lg, const float* __restrict__ te_lb,
    const float* __restrict__ mha_iw, const float* __restrict__ mha_ib,
    const float* __restrict__ mha_ow, const float* __restrict__ mha_ob,
    float* __restrict__ ws)
{
  int t = threadIdx.x;
  int blk = blockIdx.x;

  if (blk >= 1536) {
    if (blk < 1548) {
      int idx = (blk - 1536) * 256 + t;   // [0, 3072)
      int b = idx / 96, col = idx - b * 96;
      float acc = 0.f;
      for (int r = 0; r < 96; r++) {
        float fw = mha_iw[b * 288 + 192 + r]
                 + mha_iw[(b + 32) * 288 + 192 + r]
                 + mha_iw[(b + 64) * 288 + 192 + r];
        acc = fmaf(fw, mha_ow[r * 96 + col], acc);
      }
      ws[OFF_W2 + b * 96 + col] = acc;
    } else {
      if (t < 96) {
        float acc = mha_ob[t];
        for (int r = 0; r < 96; r++) acc = fmaf(mha_ib[192 + r], mha_ow[r * 96 + t], acc);
        ws[OFF_B2 + t] = acc;
      }
    }
    return;
  }

  int j = blk * 8 + (t >> 5);      // job id [0, 12288)
  int grp = j >> 12;               // 0 spatial, 1 genomic, 2 temporal
  int row = j & 4095;
  int c = t & 31;

  float val;
  const float* lg;
  const float* lb;
  if (grp == 0) {
    const float* in = spatial + (size_t)row * 256;
    float a0 = 0.f, a1 = 0.f, a2 = 0.f, a3 = 0.f;
#pragma unroll 4
    for (int k = 0; k < 256; k += 4) {
      float4 x = *(const float4*)(in + k);
      a0 = fmaf(x.x, sp_w[(k)     * 32 + c], a0);
      a1 = fmaf(x.y, sp_w[(k + 1) * 32 + c], a1);
      a2 = fmaf(x.z, sp_w[(k + 2) * 32 + c], a2);
      a3 = fmaf(x.w, sp_w[(k + 3) * 32 + c], a3);
    }
    val = sp_b[c] + ((a0 + a1) + (a2 + a3));
    lg = sp_lg; lb = sp_lb;
  } else if (grp == 1) {
    const float* in = genomic + (size_t)row * 8;
    float4 x0 = *(const float4*)(in);
    float4 x1 = *(const float4*)(in + 4);
    float a0 = ge_b[c];
    a0 = fmaf(x0.x, ge_w[0 * 32 + c], a0);
    a0 = fmaf(x0.y, ge_w[1 * 32 + c], a0);
    a0 = fmaf(x0.z, ge_w[2 * 32 + c], a0);
    a0 = fmaf(x0.w, ge_w[3 * 32 + c], a0);
    a0 = fmaf(x1.x, ge_w[4 * 32 + c], a0);
    a0 = fmaf(x1.y, ge_w[5 * 32 + c], a0);
    a0 = fmaf(x1.z, ge_w[6 * 32 + c], a0);
    a0 = fmaf(x1.w, ge_w[7 * 32 + c], a0);
    val = a0;
    lg = ge_lg; lb = ge_lb;
  } else {
    const float* in = temporal + (size_t)row * 64;
    float a0 = 0.f, a1 = 0.f, a2 = 0.f, a3 = 0.f;
#pragma unroll 4
    for (int k = 0; k < 64; k += 4) {
      float4 x = *(const float4*)(in + k);
      a0 = fmaf(x.x, te_w[(k)     * 32 + c], a0);
      a1 = fmaf(x.y, te_w[(k + 1) * 32 + c], a1);
      a2 = fmaf(x.z, te_w[(k + 2) * 32 + c], a2);
      a3 = fmaf(x.w, te_w[(k + 3) * 32 + c], a3);
    }
    val = te_b[c] + ((a0 + a1) + (a2 + a3));
    lg = te_lg; lb = te_lb;
  }

  float s1 = val, s2 = val * val;
#pragma unroll
  for (int m = 1; m < 32; m <<= 1) {
    s1 += __shfl_xor(s1, m, 32);
    s2 += __shfl_xor(s2, m, 32);
  }
  float mean = s1 * (1.f / 32.f);
  float var  = s2 * (1.f / 32.f) - mean * mean;
  float y = fmaxf((val - mean) * rsqrtf(var + 1e-5f) * lg[c] + lb[c], 0.f);
  ws[OFF_COMB + (size_t)row * 96 + grp * 32 + c] = y;
}

// ---- Kernel 2: h = comb @ gat_w; hT bf16 transpose; f1/f2 -----------------
__global__ __launch_bounds__(256) void k_proj(
    const float* __restrict__ gat_w, const float* __restrict__ gat_a,
    float* __restrict__ ws)
{
  __shared__ float h_s[4][64];
  int t = threadIdx.x;
  int w = t >> 6, d = t & 63;
  int row0 = blockIdx.x * 4;
  int row = row0 + w;

  const float* crow = ws + OFF_COMB + (size_t)row * 96;
  float a0 = 0.f, a1 = 0.f;
#pragma unroll 8
  for (int k = 0; k < 96; k += 2) {
    a0 = fmaf(crow[k],     gat_w[k * 64 + d],       a0);
    a1 = fmaf(crow[k + 1], gat_w[(k + 1) * 64 + d], a1);
  }
  float h = a0 + a1;

  int dc = d & 31;
  float p1 = h * gat_a[dc];
  float p2 = h * gat_a[32 + dc];
#pragma unroll
  for (int m = 1; m < 32; m <<= 1) {
    p1 += __shfl_xor(p1, m, 32);
    p2 += __shfl_xor(p2, m, 32);
  }
  if (dc == 0) {
    int head = d >> 5;
    ws[OFF_F1 + head * NN + row] = p1;
    ws[OFF_F2 + head * NN + row] = p2;
  }

  h_s[w][d] = h;
  __syncthreads();
  if (t < 64) {
    unsigned u0 = (unsigned)f2bf(h_s[0][t]) | ((unsigned)f2bf(h_s[1][t]) << 16);
    unsigned u1 = (unsigned)f2bf(h_s[2][t]) | ((unsigned)f2bf(h_s[3][t]) << 16);
    uint2 v; v.x = u0; v.y = u1;
    unsigned short* hT = (unsigned short*)(ws + OFF_HT);
    *(uint2*)(hT + (size_t)t * NN + row0) = v;
  }
}

// ---- Kernel 3: GAT via MFMA; bitmask adjacency; no softmax shift -----------
// Per 64-j tile: ONE u64 mask load per lane (covers both 32-j MFMA chunks).
template<int NSC>
__global__ __launch_bounds__(256) void k_gat5(
    const unsigned long long* __restrict__ pack,  // [i][64] u64
    const unsigned short* __restrict__ hT,        // bf16 [d=64][j=4096]
    const float* __restrict__ f1h,                // [head][i]
    const float* __restrict__ f2h,                // [head][j]
    float* __restrict__ part,                     // [i][NSC][64]
    float* __restrict__ lpart)                    // [i][NSC][2]
{
  constexpr int SLICE = NN / NSC;
  int t = threadIdx.x;
  int lane = t & 63, wv = t >> 6;
  int quad = lane >> 4, mrow = lane & 15;
  int ib = blockIdx.x * 64 + wv * 16;
  int i_lane = ib + mrow;
  int jb = blockIdx.y * SLICE;

  float f1v0 = f1h[i_lane];
  float f1v1 = f1h[NN + i_lane];

  f32x4 acc00 = {0.f, 0.f, 0.f, 0.f};
  f32x4 acc01 = {0.f, 0.f, 0.f, 0.f};
  f32x4 acc10 = {0.f, 0.f, 0.f, 0.f};
  f32x4 acc11 = {0.f, 0.f, 0.f, 0.f};
  float ls0 = 0.f, ls1 = 0.f;

  const unsigned long long* prow = pack + ((size_t)i_lane << 6);  // NN/64 = 64

#pragma unroll
  for (int ti = 0; ti < SLICE / 64; ti++) {
    int jt = jb + ti * 64;
    unsigned long long qm = prow[jt >> 6];
    int jq0 = jt + quad * 8;
    int jq1 = jq0 + 32;
    // f2 for both chunks, both heads
    float4 fa0 = *(const float4*)(f2h + jq0);
    float4 fb0 = *(const float4*)(f2h + jq0 + 4);
    float4 fa1 = *(const float4*)(f2h + jq1);
    float4 fb1 = *(const float4*)(f2h + jq1 + 4);
    float4 fc0 = *(const float4*)(f2h + NN + jq0);
    float4 fd0 = *(const float4*)(f2h + NN + jq0 + 4);
    float4 fc1 = *(const float4*)(f2h + NN + jq1);
    float4 fd1 = *(const float4*)(f2h + NN + jq1 + 4);
    // hT B-fragments for both chunks
    short8 b00a = *(const short8*)(hT + (size_t)(mrow)      * NN + jq0);
    short8 b01a = *(const short8*)(hT + (size_t)(16 + mrow) * NN + jq0);
    short8 b10a = *(const short8*)(hT + (size_t)(32 + mrow) * NN + jq0);
    short8 b11a = *(const short8*)(hT + (size_t)(48 + mrow) * NN + jq0);
    short8 b00b = *(const short8*)(hT + (size_t)(mrow)      * NN + jq1);
    short8 b01b = *(const short8*)(hT + (size_t)(16 + mrow) * NN + jq1);
    short8 b10b = *(const short8*)(hT + (size_t)(32 + mrow) * NN + jq1);
    short8 b11b = *(const short8*)(hT + (size_t)(48 + mrow) * NN + jq1);

    // ---- chunk 0 (bits quad*8+k) ----
    {
      float f2a[8] = {fa0.x, fa0.y, fa0.z, fa0.w, fb0.x, fb0.y, fb0.z, fb0.w};
      float f2b[8] = {fc0.x, fc0.y, fc0.z, fc0.w, fd0.x, fd0.y, fd0.z, fd0.w};
      unsigned mbits = (unsigned)(qm >> (quad * 8)) ;
      union { short8 v; unsigned short u[8]; } a0, a1;
#pragma unroll
      for (int k = 0; k < 8; k++) {
        float e0 = f1v0 + f2a[k];
        float le0 = fmaxf(e0, 0.2f * e0);
        float w0 = __builtin_amdgcn_exp2f(le0 * LOG2E);
        float e1 = f1v1 + f2b[k];
        float le1 = fmaxf(e1, 0.2f * e1);
        float w1 = __builtin_amdgcn_exp2f(le1 * LOG2E);
        bool on = (mbits >> k) & 1u;
        w0 = on ? w0 : 0.f;
        w1 = on ? w1 : 0.f;
        ls0 += w0; ls1 += w1;
        a0.u[k] = f2bf(w0);
        a1.u[k] = f2bf(w1);
      }
      acc00 = __builtin_amdgcn_mfma_f32_16x16x32_bf16(a0.v, b00a, acc00, 0, 0, 0);
      acc01 = __builtin_amdgcn_mfma_f32_16x16x32_bf16(a0.v, b01a, acc01, 0, 0, 0);
      acc10 = __builtin_amdgcn_mfma_f32_16x16x32_bf16(a1.v, b10a, acc10, 0, 0, 0);
      acc11 = __builtin_amdgcn_mfma_f32_16x16x32_bf16(a1.v, b11a, acc11, 0, 0, 0);
    }
    // ---- chunk 1 (bits 32+quad*8+k) ----
    {
      float f2a[8] = {fa1.x, fa1.y, fa1.z, fa1.w, fb1.x, fb1.y, fb1.z, fb1.w};
      float f2b[8] = {fc1.x, fc1.y, fc1.z, fc1.w, fd1.x, fd1.y, fd1.z, fd1.w};
      unsigned mbits = (unsigned)(qm >> (32 + quad * 8));
      union { short8 v; unsigned short u[8]; } a0, a1;
#pragma unroll
      for (int k = 0; k < 8; k++) {
        float e0 = f1v0 + f2a[k];
        float le0 = fmaxf(e0, 0.2f * e0);
        float w0 = __builtin_amdgcn_exp2f(le0 * LOG2E);
        float e1 = f1v1 + f2b[k];
        float le1 = fmaxf(e1, 0.2f * e1);
        float w1 = __builtin_amdgcn_exp2f(le1 * LOG2E);
        bool on = (mbits >> k) & 1u;
        w0 = on ? w0 : 0.f;
        w1 = on ? w1 : 0.f;
        ls0 += w0; ls1 += w1;
        a0.u[k] = f2bf(w0);
        a1.u[k] = f2bf(w1);
      }
      acc00 = __builtin_amdgcn_mfma_f32_16x16x32_bf16(a0.v, b00b, acc00, 0, 0, 0);
      acc01 = __builtin_amdgcn_mfma_f32_16x16x32_bf16(a0.v, b01b, acc01, 0, 0, 0);
      acc10 = __builtin_amdgcn_mfma_f32_16x16x32_bf16(a1.v, b10b, acc10, 0, 0, 0);
      acc11 = __builtin_amdgcn_mfma_f32_16x16x32_bf16(a1.v, b11b, acc11, 0, 0, 0);
    }
  }

  ls0 += __shfl_xor(ls0, 16); ls0 += __shfl_xor(ls0, 32);
  ls1 += __shfl_xor(ls1, 16); ls1 += __shfl_xor(ls1, 32);

  int slot = blockIdx.y;
#pragma unroll
  for (int r = 0; r < 4; r++) {
    int ig = ib + quad * 4 + r;
    float* p = part + (size_t)ig * (NSC * 64) + slot * 64;
    p[mrow]      = acc00[r];
    p[16 + mrow] = acc01[r];
    p[32 + mrow] = acc10[r];
    p[48 + mrow] = acc11[r];
  }
  if (lane < 16) {
    int ig = ib + lane;
    lpart[((size_t)ig * NSC + slot) * 2]     = ls0;
    lpart[((size_t)ig * NSC + slot) * 2 + 1] = ls1;
  }
}

// ---- Kernel 4: one wave per row — reduce + folded tail + towers ------------
template<int NSC>
__global__ __launch_bounds__(256) void k_post3(
    const float* __restrict__ gat_ow, const float* __restrict__ gat_ob,
    const float* __restrict__ gat_lg, const float* __restrict__ gat_lb,
    const float* __restrict__ m1_w, const float* __restrict__ m1_b,
    const float* __restrict__ m1_lg, const float* __restrict__ m1_lb,
    const float* __restrict__ m2_w, const float* __restrict__ m2_b,
    const float* __restrict__ m2_lg, const float* __restrict__ m2_lb,
    const float* __restrict__ m3_w, const float* __restrict__ m3_b,
    const float* __restrict__ c1_w, const float* __restrict__ c1_b,
    const float* __restrict__ c1_lg, const float* __restrict__ c1_lb,
    const float* __restrict__ c2_w, const float* __restrict__ c2_b,
    const float* __restrict__ c2_lg, const float* __restrict__ c2_lb,
    const float* __restrict__ c3_w, const float* __restrict__ c3_b,
    const float* __restrict__ part, const float* __restrict__ lpart,
    const float* __restrict__ comb, const float* __restrict__ W2,
    const float* __restrict__ B2,
    float* __restrict__ out)
{
  int t = threadIdx.x;
  int w = t >> 6, l = t & 63;
  int i = blockIdx.x * 4 + w;

  __shared__ float sh_h[4][64];
  __shared__ float sh_go[4][32];
  __shared__ float sh_fin[4][96];
  __shared__ float sh_t1[4][2][64];

  {
    const float* pr = part + (size_t)i * (NSC * 64);
    float a0 = 0.f, a1 = 0.f, a2 = 0.f, a3 = 0.f;
#pragma unroll
    for (int s = 0; s < NSC; s += 4) {
      a0 += pr[(s)     * 64 + l];
      a1 += pr[(s + 1) * 64 + l];
      a2 += pr[(s + 2) * 64 + l];
      a3 += pr[(s + 3) * 64 + l];
    }
    float a = (a0 + a1) + (a2 + a3);
    const float* lr = lpart + (size_t)i * NSC * 2;
    float l0 = 0.f, l1 = 0.f;
#pragma unroll
    for (int s = 0; s < NSC; s++) { l0 += lr[s * 2]; l1 += lr[s * 2 + 1]; }
    sh_h[w][l] = a / (l < 32 ? l0 : l1);
  }
  __syncthreads();

  if (l < 32) {
    float acc = gat_ob[l];
#pragma unroll 8
    for (int r = 0; r < 64; r++) acc = fmaf(sh_h[w][r], gat_ow[r * 32 + l], acc);
    float s1 = acc, s2 = acc * acc;
#pragma unroll
    for (int m = 1; m < 32; m <<= 1) {
      s1 += __shfl_xor(s1, m, 32);
      s2 += __shfl_xor(s2, m, 32);
    }
    float mean = s1 * (1.f / 32.f), var = s2 * (1.f / 32.f) - mean * mean;
    sh_go[w][l] = (acc - mean) * rsqrtf(var + 1e-5f) * gat_lg[l] + gat_lb[l];
  }
  __syncthreads();

  {
    float accA = B2[l];
#pragma unroll 8
    for (int d = 0; d < 32; d++) accA = fmaf(sh_go[w][d], W2[d * 96 + l], accA);
    sh_fin[w][l] = accA + comb[(size_t)i * 96 + l];
    if (l < 32) {
      float accB = B2[64 + l];
#pragma unroll 8
      for (int d = 0; d < 32; d++) accB = fmaf(sh_go[w][d], W2[d * 96 + 64 + l], accB);
      sh_fin[w][64 + l] = accB + comb[(size_t)i * 96 + 64 + l];
    }
  }
  __syncthreads();

  {
    float am = m1_b[l], ac = c1_b[l];
#pragma unroll 4
    for (int r = 0; r < 96; r++) {
      float f = sh_fin[w][r];
      am = fmaf(f, m1_w[r * 64 + l], am);
      ac = fmaf(f, c1_w[r * 64 + l], ac);
    }
    float s1 = am, s2 = am * am;
#pragma unroll
    for (int m = 1; m < 64; m <<= 1) { s1 += __shfl_xor(s1, m); s2 += __shfl_xor(s2, m); }
    float mean = s1 * (1.f / 64.f), var = s2 * (1.f / 64.f) - mean * mean;
    sh_t1[w][0][l] = fmaxf((am - mean) * rsqrtf(var + 1e-5f) * m1_lg[l] + m1_lb[l], 0.f);
    s1 = ac; s2 = ac * ac;
#pragma unroll
    for (int m = 1; m < 64; m <<= 1) { s1 += __shfl_xor(s1, m); s2 += __shfl_xor(s2, m); }
    mean = s1 * (1.f / 64.f); var = s2 * (1.f / 64.f) - mean * mean;
    sh_t1[w][1][l] = fmaxf((ac - mean) * rsqrtf(var + 1e-5f) * c1_lg[l] + c1_lb[l], 0.f);
  }
  __syncthreads();

  {
    int tw = l >> 5, c = l & 31;
    const float* w2  = tw ? c2_w  : m2_w;
    const float* b2  = tw ? c2_b  : m2_b;
    const float* lg2 = tw ? c2_lg : m2_lg;
    const float* lb2 = tw ? c2_lb : m2_lb;
    float a2 = b2[c];
#pragma unroll 4
    for (int r = 0; r < 64; r++) a2 = fmaf(sh_t1[w][tw][r], w2[r * 32 + c], a2);
    float u1 = a2, u2 = a2 * a2;
#pragma unroll
    for (int m = 1; m < 32; m <<= 1) {
      u1 += __shfl_xor(u1, m, 32);
      u2 += __shfl_xor(u2, m, 32);
    }
    float mean = u1 * (1.f / 32.f), var = u2 * (1.f / 32.f) - mean * mean;
    float y2 = fmaxf((a2 - mean) * rsqrtf(var + 1e-5f) * lg2[c] + lb2[c], 0.f);
    float p = y2 * (tw ? c3_w[c] : m3_w[c]);
#pragma unroll
    for (int m = 1; m < 32; m <<= 1) p += __shfl_xor(p, m, 32);
    if (c == 0) {
      float v = p + (tw ? c3_b[0] : m3_b[0]);
      if (tw) out[NN + i] = 1.f / (1.f + expf(-v));
      else    out[i] = v;
    }
  }
}

extern "C" void kernel_launch(void* const* d_in, const int* in_sizes, int n_in,
                              void* d_out, int out_size, void* d_ws, size_t ws_size,
                              hipStream_t stream) {
  (void)in_sizes; (void)n_in; (void)out_size;
  const float* spatial  = (const float*)d_in[0];
  const float* genomic  = (const float*)d_in[1];
  const float* temporal = (const float*)d_in[2];
  const int*   adj      = (const int*)d_in[3];
  const float* sp_w = (const float*)d_in[4];
  const float* sp_b = (const float*)d_in[5];
  const float* sp_lg = (const float*)d_in[6];
  const float* sp_lb = (const float*)d_in[7];
  const float* ge_w = (const float*)d_in[8];
  const float* ge_b = (const float*)d_in[9];
  const float* ge_lg = (const float*)d_in[10];
  const float* ge_lb = (const float*)d_in[11];
  const float* te_w = (const float*)d_in[12];
  const float* te_b = (const float*)d_in[13];
  const float* te_lg = (const float*)d_in[14];
  const float* te_lb = (const float*)d_in[15];
  const float* gat_w = (const float*)d_in[16];
  const float* gat_a = (const float*)d_in[17];
  const float* gat_ow = (const float*)d_in[18];
  const float* gat_ob = (const float*)d_in[19];
  const float* gat_lg = (const float*)d_in[20];
  const float* gat_lb = (const float*)d_in[21];
  const float* mha_iw = (const float*)d_in[22];
  const float* mha_ib = (const float*)d_in[23];
  const float* mha_ow = (const float*)d_in[24];
  const float* mha_ob = (const float*)d_in[25];
  const float* m1_w = (const float*)d_in[26];
  const float* m1_b = (const float*)d_in[27];
  const float* m1_lg = (const float*)d_in[28];
  const float* m1_lb = (const float*)d_in[29];
  const float* m2_w = (const float*)d_in[30];
  const float* m2_b = (const float*)d_in[31];
  const float* m2_lg = (const float*)d_in[32];
  const float* m2_lb = (const float*)d_in[33];
  const float* m3_w = (const float*)d_in[34];
  const float* m3_b = (const float*)d_in[35];
  const float* c1_w = (const float*)d_in[36];
  const float* c1_b = (const float*)d_in[37];
  const float* c1_lg = (const float*)d_in[38];
  const float* c1_lb = (const float*)d_in[39];
  const float* c2_w = (const float*)d_in[40];
  const float* c2_b = (const float*)d_in[41];
  const float* c2_lg = (const float*)d_in[42];
  const float* c2_lb = (const float*)d_in[43];
  const float* c3_w = (const float*)d_in[44];
  const float* c3_b = (const float*)d_in[45];

  float* ws  = (float*)d_ws;
  float* out = (float*)d_out;
  float* part = ws + OFF_PART;

  k_pack<<<(NN * NN) / 256, 256, 0, stream>>>(adj, (unsigned long long*)(ws + OFF_PACK));
  k_comb<<<1549, 256, 0, stream>>>(spatial, genomic, temporal,
                                   sp_w, sp_b, sp_lg, sp_lb,
                                   ge_w, ge_b, ge_lg, ge_lb,
                                   te_w, te_b, te_lg, te_lb,
                                   mha_iw, mha_ib, mha_ow, mha_ob, ws);
  k_proj<<<NN / 4, 256, 0, stream>>>(gat_w, gat_a, ws);

  size_t need16 = (size_t)(OFF_PART + 16ul * NN * 64 + 16ul * NN * 2) * 4;
  if (ws_size >= need16) {
    float* lpart = part + 16ul * NN * 64;
    dim3 g2(NN / 64, 16);
    k_gat5<16><<<g2, 256, 0, stream>>>((const unsigned long long*)(ws + OFF_PACK),
                                       (const unsigned short*)(ws + OFF_HT),
                                       ws + OFF_F1, ws + OFF_F2, part, lpart);
    k_post3<16><<<NN / 4, 256, 0, stream>>>(gat_ow, gat_ob, gat_lg, gat_lb,
                                            m1_w, m1_b, m1_lg, m1_lb,
                                            m2_w, m2_b, m2_lg, m2_lb,
                                            m3_w, m3_b,
                                            c1_w, c1_b, c1_lg, c1_lb,
                                            c2_w, c2_b, c2_lg, c2_lb,
                                            c3_w, c3_b,
                                            part, lpart, ws + OFF_COMB,
                                            ws + OFF_W2, ws + OFF_B2, out);
  } else {
    float* lpart = part + 8ul * NN * 64;
    dim3 g2(NN / 64, 8);
    k_gat5<8><<<g2, 256, 0, stream>>>((const unsigned long long*)(ws + OFF_PACK),
                                      (const unsigned short*)(ws + OFF_HT),
                                      ws + OFF_F1, ws + OFF_F2, part, lpart);
    k_post3<8><<<NN / 4, 256, 0, stream>>>(gat_ow, gat_ob, gat_lg, gat_lb,
                                           m1_w, m1_b, m1_lg, m1_lb,
                                           m2_w, m2_b, m2_lg, m2_lb,
                                           m3_w, m3_b,
                                           c1_w, c1_b, c1_lg, c1_lb,
                                           c2_w, c2_b, c2_lg, c2_lb,
                                           c3_w, c3_b,
                                           part, lpart, ws + OFF_COMB,
                                           ws + OFF_W2, ws + OFF_B2, out);
  }
}

// Round 8
// 237.973 us; speedup vs baseline: 1.1409x; 1.1409x over previous
//
#include <hip/hip_runtime.h>
#include <math.h>

#define NN 4096
#define LOG2E 1.4426950408889634f

typedef short short8 __attribute__((ext_vector_type(8)));
typedef float f32x4 __attribute__((ext_vector_type(4)));

// workspace layout (float offsets)
#define OFF_COMB   0u          // 4096*96
#define OFF_F1     393216u     // [head][i] 2*4096  (pre-scaled by LOG2E)
#define OFF_F2     401408u     // [head][j] 2*4096  (pre-scaled by LOG2E)
#define OFF_W2     409616u     // 32*96
#define OFF_B2     412688u     // 96 (+pad to 412800)
#define OFF_HT     412800u     // bf16 hT[64][4096] = 131072 float slots
#define OFF_HT2    543872u     // bf16 HT2 fragment-major [64 tiles][4096] = 131072 slots
#define OFF_PART   674944u     // part[i][NS][64], then lpart[i][NS][2]

__device__ inline unsigned short f2bf(float x) {
  unsigned u = __float_as_uint(x);
  return (unsigned short)((u + 0x8000u) >> 16);   // round-half-up
}

// ---- Kernel 1: comb = relu(LN(embed)); tail blocks fold W2/B2 (mha path) ----
__global__ __launch_bounds__(256) void k_comb(
    const float* __restrict__ spatial, const float* __restrict__ genomic,
    const float* __restrict__ temporal,
    const float* __restrict__ sp_w, const float* __restrict__ sp_b,
    const float* __restrict__ sp_lg, const float* __restrict__ sp_lb,
    const float* __restrict__ ge_w, const float* __restrict__ ge_b,
    const float* __restrict__ ge_lg, const float* __restrict__ ge_lb,
    const float* __restrict__ te_w, const float* __restrict__ te_b,
    const float* __restrict__ te_lg, const float* __restrict__ te_lb,
    const float* __restrict__ mha_iw, const float* __restrict__ mha_ib,
    const float* __restrict__ mha_ow, const float* __restrict__ mha_ob,
    float* __restrict__ ws)
{
  int t = threadIdx.x;
  int blk = blockIdx.x;

  if (blk >= 1536) {
    if (blk < 1548) {
      int idx = (blk - 1536) * 256 + t;   // [0, 3072)
      int b = idx / 96, col = idx - b * 96;
      float acc = 0.f;
      for (int r = 0; r < 96; r++) {
        float fw = mha_iw[b * 288 + 192 + r]
                 + mha_iw[(b + 32) * 288 + 192 + r]
                 + mha_iw[(b + 64) * 288 + 192 + r];
        acc = fmaf(fw, mha_ow[r * 96 + col], acc);
      }
      ws[OFF_W2 + b * 96 + col] = acc;
    } else {
      if (t < 96) {
        float acc = mha_ob[t];
        for (int r = 0; r < 96; r++) acc = fmaf(mha_ib[192 + r], mha_ow[r * 96 + t], acc);
        ws[OFF_B2 + t] = acc;
      }
    }
    return;
  }

  int j = blk * 8 + (t >> 5);      // job id [0, 12288)
  int grp = j >> 12;               // 0 spatial, 1 genomic, 2 temporal
  int row = j & 4095;
  int c = t & 31;

  float val;
  const float* lg;
  const float* lb;
  if (grp == 0) {
    const float* in = spatial + (size_t)row * 256;
    float a0 = 0.f, a1 = 0.f, a2 = 0.f, a3 = 0.f;
#pragma unroll 4
    for (int k = 0; k < 256; k += 4) {
      float4 x = *(const float4*)(in + k);
      a0 = fmaf(x.x, sp_w[(k)     * 32 + c], a0);
      a1 = fmaf(x.y, sp_w[(k + 1) * 32 + c], a1);
      a2 = fmaf(x.z, sp_w[(k + 2) * 32 + c], a2);
      a3 = fmaf(x.w, sp_w[(k + 3) * 32 + c], a3);
    }
    val = sp_b[c] + ((a0 + a1) + (a2 + a3));
    lg = sp_lg; lb = sp_lb;
  } else if (grp == 1) {
    const float* in = genomic + (size_t)row * 8;
    float4 x0 = *(const float4*)(in);
    float4 x1 = *(const float4*)(in + 4);
    float a0 = ge_b[c];
    a0 = fmaf(x0.x, ge_w[0 * 32 + c], a0);
    a0 = fmaf(x0.y, ge_w[1 * 32 + c], a0);
    a0 = fmaf(x0.z, ge_w[2 * 32 + c], a0);
    a0 = fmaf(x0.w, ge_w[3 * 32 + c], a0);
    a0 = fmaf(x1.x, ge_w[4 * 32 + c], a0);
    a0 = fmaf(x1.y, ge_w[5 * 32 + c], a0);
    a0 = fmaf(x1.z, ge_w[6 * 32 + c], a0);
    a0 = fmaf(x1.w, ge_w[7 * 32 + c], a0);
    val = a0;
    lg = ge_lg; lb = ge_lb;
  } else {
    const float* in = temporal + (size_t)row * 64;
    float a0 = 0.f, a1 = 0.f, a2 = 0.f, a3 = 0.f;
#pragma unroll 4
    for (int k = 0; k < 64; k += 4) {
      float4 x = *(const float4*)(in + k);
      a0 = fmaf(x.x, te_w[(k)     * 32 + c], a0);
      a1 = fmaf(x.y, te_w[(k + 1) * 32 + c], a1);
      a2 = fmaf(x.z, te_w[(k + 2) * 32 + c], a2);
      a3 = fmaf(x.w, te_w[(k + 3) * 32 + c], a3);
    }
    val = te_b[c] + ((a0 + a1) + (a2 + a3));
    lg = te_lg; lb = te_lb;
  }

  float s1 = val, s2 = val * val;
#pragma unroll
  for (int m = 1; m < 32; m <<= 1) {
    s1 += __shfl_xor(s1, m, 32);
    s2 += __shfl_xor(s2, m, 32);
  }
  float mean = s1 * (1.f / 32.f);
  float var  = s2 * (1.f / 32.f) - mean * mean;
  float y = fmaxf((val - mean) * rsqrtf(var + 1e-5f) * lg[c] + lb[c], 0.f);
  ws[OFF_COMB + (size_t)row * 96 + grp * 32 + c] = y;
}

// ---- Kernel 2: h = comb @ gat_w; hT bf16 transpose; f1/f2 (LOG2E-scaled) ---
__global__ __launch_bounds__(256) void k_proj(
    const float* __restrict__ gat_w, const float* __restrict__ gat_a,
    float* __restrict__ ws)
{
  __shared__ float h_s[4][64];
  int t = threadIdx.x;
  int w = t >> 6, d = t & 63;
  int row0 = blockIdx.x * 4;
  int row = row0 + w;

  const float* crow = ws + OFF_COMB + (size_t)row * 96;
  float a0 = 0.f, a1 = 0.f;
#pragma unroll 8
  for (int k = 0; k < 96; k += 2) {
    a0 = fmaf(crow[k],     gat_w[k * 64 + d],       a0);
    a1 = fmaf(crow[k + 1], gat_w[(k + 1) * 64 + d], a1);
  }
  float h = a0 + a1;

  int dc = d & 31;
  float p1 = h * gat_a[dc];
  float p2 = h * gat_a[32 + dc];
#pragma unroll
  for (int m = 1; m < 32; m <<= 1) {
    p1 += __shfl_xor(p1, m, 32);
    p2 += __shfl_xor(p2, m, 32);
  }
  if (dc == 0) {
    int head = d >> 5;
    ws[OFF_F1 + head * NN + row] = p1 * LOG2E;
    ws[OFF_F2 + head * NN + row] = p2 * LOG2E;
  }

  h_s[w][d] = h;
  __syncthreads();
  if (t < 64) {
    unsigned u0 = (unsigned)f2bf(h_s[0][t]) | ((unsigned)f2bf(h_s[1][t]) << 16);
    unsigned u1 = (unsigned)f2bf(h_s[2][t]) | ((unsigned)f2bf(h_s[3][t]) << 16);
    uint2 v; v.x = u0; v.y = u1;
    unsigned short* hT = (unsigned short*)(ws + OFF_HT);
    *(uint2*)(hT + (size_t)t * NN + row0) = v;
  }
}

// ---- Kernel 2b: repack hT[d][j] -> HT2 fragment-major (coalesced both sides)
// Run R = T*512 + (c*4+g)*64 + l  (l = quad*16+mrow): 8 bf16 from
// hT[d = g*16+mrow][j0 = T*64 + c*32 + quad*8 .. +8] -> HT2[R*8 .. +8]
__global__ __launch_bounds__(256) void k_repack(float* __restrict__ ws)
{
  const unsigned short* hT = (const unsigned short*)(ws + OFF_HT);
  unsigned short* hT2 = (unsigned short*)(ws + OFF_HT2);
  int R = blockIdx.x * 256 + threadIdx.x;      // 0..32767
  int T = R >> 9;
  int r = R & 511;
  int c = r >> 8;
  int g = (r >> 6) & 3;
  int l = r & 63;
  int quad = l >> 4, mrow = l & 15;
  int j0 = T * 64 + c * 32 + quad * 8;
  int d  = g * 16 + mrow;
  short8 v = *(const short8*)(hT + (size_t)d * NN + j0);
  *(short8*)(hT2 + (size_t)R * 8) = v;
}

// ---- Kernel 3: GAT via MFMA; adjacency fused via per-wave ballot ----------
template<int NSC>
__global__ __launch_bounds__(256) void k_gat6(
    const int* __restrict__ adj,
    const unsigned short* __restrict__ hT2,  // fragment-major
    const float* __restrict__ f1h,           // [head][i], LOG2E-scaled
    const float* __restrict__ f2h,           // [head][j], LOG2E-scaled
    float* __restrict__ part,                // [i][NSC][64]
    float* __restrict__ lpart)               // [i][NSC][2]
{
  constexpr int SLICE = NN / NSC;
  int t = threadIdx.x;
  int lane = t & 63, wv = t >> 6;
  int quad = lane >> 4, mrow = lane & 15;
  int ib = blockIdx.x * 64 + wv * 16;
  int i_lane = ib + mrow;
  int jb = blockIdx.y * SLICE;

  float f1v0 = f1h[i_lane];
  float f1v1 = f1h[NN + i_lane];

  f32x4 acc00 = {0.f, 0.f, 0.f, 0.f};
  f32x4 acc01 = {0.f, 0.f, 0.f, 0.f};
  f32x4 acc10 = {0.f, 0.f, 0.f, 0.f};
  f32x4 acc11 = {0.f, 0.f, 0.f, 0.f};
  float ls0 = 0.f, ls1 = 0.f;

  const int* adjT = adj + (size_t)ib * NN;

#pragma unroll
  for (int ti = 0; ti < SLICE / 64; ti++) {
    int jt = jb + ti * 64;

    // --- adjacency: 16 coalesced row-loads + ballot-pack into qm ---
    unsigned long long qm = 0;
#pragma unroll
    for (int r = 0; r < 16; r++) {
      int av = adjT[(size_t)r * NN + jt + lane];
      unsigned long long b = __ballot(av != 0);
      if (mrow == r) qm = b;
    }

    // --- B fragments: fully coalesced from fragment-major HT2 ---
    const unsigned short* hb = hT2 + ((size_t)(jt >> 6)) * 4096;
    short8 b00a = *(const short8*)(hb + (0 * 4 + 0) * 512 + lane * 8);
    short8 b01a = *(const short8*)(hb + (0 * 4 + 1) * 512 + lane * 8);
    short8 b10a = *(const short8*)(hb + (0 * 4 + 2) * 512 + lane * 8);
    short8 b11a = *(const short8*)(hb + (0 * 4 + 3) * 512 + lane * 8);
    short8 b00b = *(const short8*)(hb + (1 * 4 + 0) * 512 + lane * 8);
    short8 b01b = *(const short8*)(hb + (1 * 4 + 1) * 512 + lane * 8);
    short8 b10b = *(const short8*)(hb + (1 * 4 + 2) * 512 + lane * 8);
    short8 b11b = *(const short8*)(hb + (1 * 4 + 3) * 512 + lane * 8);

    int jq0 = jt + quad * 8;
    int jq1 = jq0 + 32;
    float4 fa0 = *(const float4*)(f2h + jq0);
    float4 fb0 = *(const float4*)(f2h + jq0 + 4);
    float4 fa1 = *(const float4*)(f2h + jq1);
    float4 fb1 = *(const float4*)(f2h + jq1 + 4);
    float4 fc0 = *(const float4*)(f2h + NN + jq0);
    float4 fd0 = *(const float4*)(f2h + NN + jq0 + 4);
    float4 fc1 = *(const float4*)(f2h + NN + jq1);
    float4 fd1 = *(const float4*)(f2h + NN + jq1 + 4);

    // ---- chunk 0 ----
    {
      float f2a[8] = {fa0.x, fa0.y, fa0.z, fa0.w, fb0.x, fb0.y, fb0.z, fb0.w};
      float f2b[8] = {fc0.x, fc0.y, fc0.z, fc0.w, fd0.x, fd0.y, fd0.z, fd0.w};
      unsigned mbits = (unsigned)(qm >> (quad * 8));
      union { short8 v; unsigned short u[8]; } a0, a1;
#pragma unroll
      for (int k = 0; k < 8; k++) {
        float e0 = f1v0 + f2a[k];
        float w0 = __builtin_amdgcn_exp2f(fmaxf(e0, 0.2f * e0));
        float e1 = f1v1 + f2b[k];
        float w1 = __builtin_amdgcn_exp2f(fmaxf(e1, 0.2f * e1));
        bool on = (mbits >> k) & 1u;
        w0 = on ? w0 : 0.f;
        w1 = on ? w1 : 0.f;
        ls0 += w0; ls1 += w1;
        a0.u[k] = f2bf(w0);
        a1.u[k] = f2bf(w1);
      }
      acc00 = __builtin_amdgcn_mfma_f32_16x16x32_bf16(a0.v, b00a, acc00, 0, 0, 0);
      acc01 = __builtin_amdgcn_mfma_f32_16x16x32_bf16(a0.v, b01a, acc01, 0, 0, 0);
      acc10 = __builtin_amdgcn_mfma_f32_16x16x32_bf16(a1.v, b10a, acc10, 0, 0, 0);
      acc11 = __builtin_amdgcn_mfma_f32_16x16x32_bf16(a1.v, b11a, acc11, 0, 0, 0);
    }
    // ---- chunk 1 ----
    {
      float f2a[8] = {fa1.x, fa1.y, fa1.z, fa1.w, fb1.x, fb1.y, fb1.z, fb1.w};
      float f2b[8] = {fc1.x, fc1.y, fc1.z, fc1.w, fd1.x, fd1.y, fd1.z, fd1.w};
      unsigned mbits = (unsigned)(qm >> (32 + quad * 8));
      union { short8 v; unsigned short u[8]; } a0, a1;
#pragma unroll
      for (int k = 0; k < 8; k++) {
        float e0 = f1v0 + f2a[k];
        float w0 = __builtin_amdgcn_exp2f(fmaxf(e0, 0.2f * e0));
        float e1 = f1v1 + f2b[k];
        float w1 = __builtin_amdgcn_exp2f(fmaxf(e1, 0.2f * e1));
        bool on = (mbits >> k) & 1u;
        w0 = on ? w0 : 0.f;
        w1 = on ? w1 : 0.f;
        ls0 += w0; ls1 += w1;
        a0.u[k] = f2bf(w0);
        a1.u[k] = f2bf(w1);
      }
      acc00 = __builtin_amdgcn_mfma_f32_16x16x32_bf16(a0.v, b00b, acc00, 0, 0, 0);
      acc01 = __builtin_amdgcn_mfma_f32_16x16x32_bf16(a0.v, b01b, acc01, 0, 0, 0);
      acc10 = __builtin_amdgcn_mfma_f32_16x16x32_bf16(a1.v, b10b, acc10, 0, 0, 0);
      acc11 = __builtin_amdgcn_mfma_f32_16x16x32_bf16(a1.v, b11b, acc11, 0, 0, 0);
    }
  }

  ls0 += __shfl_xor(ls0, 16); ls0 += __shfl_xor(ls0, 32);
  ls1 += __shfl_xor(ls1, 16); ls1 += __shfl_xor(ls1, 32);

  int slot = blockIdx.y;
#pragma unroll
  for (int r = 0; r < 4; r++) {
    int ig = ib + quad * 4 + r;
    float* p = part + (size_t)ig * (NSC * 64) + slot * 64;
    p[mrow]      = acc00[r];
    p[16 + mrow] = acc01[r];
    p[32 + mrow] = acc10[r];
    p[48 + mrow] = acc11[r];
  }
  if (lane < 16) {
    int ig = ib + lane;
    lpart[((size_t)ig * NSC + slot) * 2]     = ls0;
    lpart[((size_t)ig * NSC + slot) * 2 + 1] = ls1;
  }
}

// ---- Kernel 4: one wave per row — reduce + folded tail + towers ------------
template<int NSC>
__global__ __launch_bounds__(256) void k_post3(
    const float* __restrict__ gat_ow, const float* __restrict__ gat_ob,
    const float* __restrict__ gat_lg, const float* __restrict__ gat_lb,
    const float* __restrict__ m1_w, const float* __restrict__ m1_b,
    const float* __restrict__ m1_lg, const float* __restrict__ m1_lb,
    const float* __restrict__ m2_w, const float* __restrict__ m2_b,
    const float* __restrict__ m2_lg, const float* __restrict__ m2_lb,
    const float* __restrict__ m3_w, const float* __restrict__ m3_b,
    const float* __restrict__ c1_w, const float* __restrict__ c1_b,
    const float* __restrict__ c1_lg, const float* __restrict__ c1_lb,
    const float* __restrict__ c2_w, const float* __restrict__ c2_b,
    const float* __restrict__ c2_lg, const float* __restrict__ c2_lb,
    const float* __restrict__ c3_w, const float* __restrict__ c3_b,
    const float* __restrict__ part, const float* __restrict__ lpart,
    const float* __restrict__ comb, const float* __restrict__ W2,
    const float* __restrict__ B2,
    float* __restrict__ out)
{
  int t = threadIdx.x;
  int w = t >> 6, l = t & 63;
  int i = blockIdx.x * 4 + w;

  __shared__ float sh_h[4][64];
  __shared__ float sh_go[4][32];
  __shared__ float sh_fin[4][96];
  __shared__ float sh_t1[4][2][64];

  {
    const float* pr = part + (size_t)i * (NSC * 64);
    float a0 = 0.f, a1 = 0.f, a2 = 0.f, a3 = 0.f;
#pragma unroll
    for (int s = 0; s < NSC; s += 4) {
      a0 += pr[(s)     * 64 + l];
      a1 += pr[(s + 1) * 64 + l];
      a2 += pr[(s + 2) * 64 + l];
      a3 += pr[(s + 3) * 64 + l];
    }
    float a = (a0 + a1) + (a2 + a3);
    const float* lr = lpart + (size_t)i * NSC * 2;
    float l0 = 0.f, l1 = 0.f;
#pragma unroll
    for (int s = 0; s < NSC; s++) { l0 += lr[s * 2]; l1 += lr[s * 2 + 1]; }
    sh_h[w][l] = a / (l < 32 ? l0 : l1);
  }
  __syncthreads();

  if (l < 32) {
    float acc = gat_ob[l];
#pragma unroll 8
    for (int r = 0; r < 64; r++) acc = fmaf(sh_h[w][r], gat_ow[r * 32 + l], acc);
    float s1 = acc, s2 = acc * acc;
#pragma unroll
    for (int m = 1; m < 32; m <<= 1) {
      s1 += __shfl_xor(s1, m, 32);
      s2 += __shfl_xor(s2, m, 32);
    }
    float mean = s1 * (1.f / 32.f), var = s2 * (1.f / 32.f) - mean * mean;
    sh_go[w][l] = (acc - mean) * rsqrtf(var + 1e-5f) * gat_lg[l] + gat_lb[l];
  }
  __syncthreads();

  {
    float accA = B2[l];
#pragma unroll 8
    for (int d = 0; d < 32; d++) accA = fmaf(sh_go[w][d], W2[d * 96 + l], accA);
    sh_fin[w][l] = accA + comb[(size_t)i * 96 + l];
    if (l < 32) {
      float accB = B2[64 + l];
#pragma unroll 8
      for (int d = 0; d < 32; d++) accB = fmaf(sh_go[w][d], W2[d * 96 + 64 + l], accB);
      sh_fin[w][64 + l] = accB + comb[(size_t)i * 96 + 64 + l];
    }
  }
  __syncthreads();

  {
    float am = m1_b[l], ac = c1_b[l];
#pragma unroll 4
    for (int r = 0; r < 96; r++) {
      float f = sh_fin[w][r];
      am = fmaf(f, m1_w[r * 64 + l], am);
      ac = fmaf(f, c1_w[r * 64 + l], ac);
    }
    float s1 = am, s2 = am * am;
#pragma unroll
    for (int m = 1; m < 64; m <<= 1) { s1 += __shfl_xor(s1, m); s2 += __shfl_xor(s2, m); }
    float mean = s1 * (1.f / 64.f), var = s2 * (1.f / 64.f) - mean * mean;
    sh_t1[w][0][l] = fmaxf((am - mean) * rsqrtf(var + 1e-5f) * m1_lg[l] + m1_lb[l], 0.f);
    s1 = ac; s2 = ac * ac;
#pragma unroll
    for (int m = 1; m < 64; m <<= 1) { s1 += __shfl_xor(s1, m); s2 += __shfl_xor(s2, m); }
    mean = s1 * (1.f / 64.f); var = s2 * (1.f / 64.f) - mean * mean;
    sh_t1[w][1][l] = fmaxf((ac - mean) * rsqrtf(var + 1e-5f) * c1_lg[l] + c1_lb[l], 0.f);
  }
  __syncthreads();

  {
    int tw = l >> 5, c = l & 31;
    const float* w2  = tw ? c2_w  : m2_w;
    const float* b2  = tw ? c2_b  : m2_b;
    const float* lg2 = tw ? c2_lg : m2_lg;
    const float* lb2 = tw ? c2_lb : m2_lb;
    float a2 = b2[c];
#pragma unroll 4
    for (int r = 0; r < 64; r++) a2 = fmaf(sh_t1[w][tw][r], w2[r * 32 + c], a2);
    float u1 = a2, u2 = a2 * a2;
#pragma unroll
    for (int m = 1; m < 32; m <<= 1) {
      u1 += __shfl_xor(u1, m, 32);
      u2 += __shfl_xor(u2, m, 32);
    }
    float mean = u1 * (1.f / 32.f), var = u2 * (1.f / 32.f) - mean * mean;
    float y2 = fmaxf((a2 - mean) * rsqrtf(var + 1e-5f) * lg2[c] + lb2[c], 0.f);
    float p = y2 * (tw ? c3_w[c] : m3_w[c]);
#pragma unroll
    for (int m = 1; m < 32; m <<= 1) p += __shfl_xor(p, m, 32);
    if (c == 0) {
      float v = p + (tw ? c3_b[0] : m3_b[0]);
      if (tw) out[NN + i] = 1.f / (1.f + expf(-v));
      else    out[i] = v;
    }
  }
}

extern "C" void kernel_launch(void* const* d_in, const int* in_sizes, int n_in,
                              void* d_out, int out_size, void* d_ws, size_t ws_size,
                              hipStream_t stream) {
  (void)in_sizes; (void)n_in; (void)out_size;
  const float* spatial  = (const float*)d_in[0];
  const float* genomic  = (const float*)d_in[1];
  const float* temporal = (const float*)d_in[2];
  const int*   adj      = (const int*)d_in[3];
  const float* sp_w = (const float*)d_in[4];
  const float* sp_b = (const float*)d_in[5];
  const float* sp_lg = (const float*)d_in[6];
  const float* sp_lb = (const float*)d_in[7];
  const float* ge_w = (const float*)d_in[8];
  const float* ge_b = (const float*)d_in[9];
  const float* ge_lg = (const float*)d_in[10];
  const float* ge_lb = (const float*)d_in[11];
  const float* te_w = (const float*)d_in[12];
  const float* te_b = (const float*)d_in[13];
  const float* te_lg = (const float*)d_in[14];
  const float* te_lb = (const float*)d_in[15];
  const float* gat_w = (const float*)d_in[16];
  const float* gat_a = (const float*)d_in[17];
  const float* gat_ow = (const float*)d_in[18];
  const float* gat_ob = (const float*)d_in[19];
  const float* gat_lg = (const float*)d_in[20];
  const float* gat_lb = (const float*)d_in[21];
  const float* mha_iw = (const float*)d_in[22];
  const float* mha_ib = (const float*)d_in[23];
  const float* mha_ow = (const float*)d_in[24];
  const float* mha_ob = (const float*)d_in[25];
  const float* m1_w = (const float*)d_in[26];
  const float* m1_b = (const float*)d_in[27];
  const float* m1_lg = (const float*)d_in[28];
  const float* m1_lb = (const float*)d_in[29];
  const float* m2_w = (const float*)d_in[30];
  const float* m2_b = (const float*)d_in[31];
  const float* m2_lg = (const float*)d_in[32];
  const float* m2_lb = (const float*)d_in[33];
  const float* m3_w = (const float*)d_in[34];
  const float* m3_b = (const float*)d_in[35];
  const float* c1_w = (const float*)d_in[36];
  const float* c1_b = (const float*)d_in[37];
  const float* c1_lg = (const float*)d_in[38];
  const float* c1_lb = (const float*)d_in[39];
  const float* c2_w = (const float*)d_in[40];
  const float* c2_b = (const float*)d_in[41];
  const float* c2_lg = (const float*)d_in[42];
  const float* c2_lb = (const float*)d_in[43];
  const float* c3_w = (const float*)d_in[44];
  const float* c3_b = (const float*)d_in[45];

  float* ws  = (float*)d_ws;
  float* out = (float*)d_out;
  float* part = ws + OFF_PART;

  k_comb<<<1549, 256, 0, stream>>>(spatial, genomic, temporal,
                                   sp_w, sp_b, sp_lg, sp_lb,
                                   ge_w, ge_b, ge_lg, ge_lb,
                                   te_w, te_b, te_lg, te_lb,
                                   mha_iw, mha_ib, mha_ow, mha_ob, ws);
  k_proj<<<NN / 4, 256, 0, stream>>>(gat_w, gat_a, ws);
  k_repack<<<128, 256, 0, stream>>>(ws);

  size_t need16 = (size_t)(OFF_PART + 16ul * NN * 64 + 16ul * NN * 2) * 4;
  if (ws_size >= need16) {
    float* lpart = part + 16ul * NN * 64;
    dim3 g2(NN / 64, 16);
    k_gat6<16><<<g2, 256, 0, stream>>>(adj,
                                       (const unsigned short*)(ws + OFF_HT2),
                                       ws + OFF_F1, ws + OFF_F2, part, lpart);
    k_post3<16><<<NN / 4, 256, 0, stream>>>(gat_ow, gat_ob, gat_lg, gat_lb,
                                            m1_w, m1_b, m1_lg, m1_lb,
                                            m2_w, m2_b, m2_lg, m2_lb,
                                            m3_w, m3_b,
                                            c1_w, c1_b, c1_lg, c1_lb,
                                            c2_w, c2_b, c2_lg, c2_lb,
                                            c3_w, c3_b,
                                            part, lpart, ws + OFF_COMB,
                                            ws + OFF_W2, ws + OFF_B2, out);
  } else {
    float* lpart = part + 8ul * NN * 64;
    dim3 g2(NN / 64, 8);
    k_gat6<8><<<g2, 256, 0, stream>>>(adj,
                                      (const unsigned short*)(ws + OFF_HT2),
                                      ws + OFF_F1, ws + OFF_F2, part, lpart);
    k_post3<8><<<NN / 4, 256, 0, stream>>>(gat_ow, gat_ob, gat_lg, gat_lb,
                                           m1_w, m1_b, m1_lg, m1_lb,
                                           m2_w, m2_b, m2_lg, m2_lb,
                                           m3_w, m3_b,
                                           c1_w, c1_b, c1_lg, c1_lb,
                                           c2_w, c2_b, c2_lg, c2_lb,
                                           c3_w, c3_b,
                                           part, lpart, ws + OFF_COMB,
                                           ws + OFF_W2, ws + OFF_B2, out);
  }
}